// Round 12
// baseline (195.172 us; speedup 1.0000x reference)
//
#include <hip/hip_runtime.h>
#include <hip/hip_bf16.h>
#include <stdint.h>

#define B_DIM   4096
#define IN_DIM  4096
#define OUT_DIM 4096
#define K_SEL   128

typedef unsigned short u16;
typedef __bf16 bf16x8 __attribute__((ext_vector_type(8)));
typedef float  f32x16 __attribute__((ext_vector_type(16)));

static __device__ __forceinline__ u16 f2bf(float f) {
    uint32_t u = __builtin_bit_cast(uint32_t, f);
    uint32_t r = (u + 0x7fffu + ((u >> 16) & 1u)) >> 16;
    return (u16)r;
}

// ---------------------------------------------------------------------------
// K1: column sums of W (fp64 partials over 8-row chunks) + W -> bf16.
// 2048 blocks = (4 col-chunks x 512 row-chunks); part = [512][4096] dbl (16MB).
// ---------------------------------------------------------------------------
__global__ __launch_bounds__(256) void colsum_conv(const float* __restrict__ W,
                                                   double* __restrict__ part,
                                                   u16* __restrict__ Wb) {
    int cb = blockIdx.x & 3;
    int rb = blockIdx.x >> 2;          // 0..511
    int c4 = cb * 256 + threadIdx.x;   // float4 index within a row
    int row0 = rb * 8;
    double s0 = 0.0, s1 = 0.0, s2 = 0.0, s3 = 0.0;
    for (int r = 0; r < 8; ++r) {
        const float4 v = ((const float4*)(W + (size_t)(row0 + r) * IN_DIM))[c4];
        s0 += (double)v.x; s1 += (double)v.y; s2 += (double)v.z; s3 += (double)v.w;
        ushort4 o;
        o.x = f2bf(v.x); o.y = f2bf(v.y); o.z = f2bf(v.z); o.w = f2bf(v.w);
        ((ushort4*)(Wb + (size_t)(row0 + r) * IN_DIM))[c4] = o;
    }
    double4 d; d.x = s0; d.y = s1; d.z = s2; d.w = s3;
    ((double4*)(part + (size_t)rb * IN_DIM))[c4] = d;
}

// 256 blocks x 256 threads: block handles 16 cols; 16 row-groups of 32.
__global__ __launch_bounds__(256) void colsum_final(const double* __restrict__ part,
                                                    float* __restrict__ cs) {
    __shared__ double red[256];
    const int t = threadIdx.x;
    const int c = blockIdx.x * 16 + (t & 15);
    const int g = t >> 4;              // 0..15
    double s = 0.0;
    for (int r = 0; r < 32; ++r) s += part[(size_t)(g * 32 + r) * IN_DIM + c];
    red[t] = s;
    __syncthreads();
    for (int off = 128; off >= 16; off >>= 1) {
        if (t < off) red[t] += red[t + off];
        __syncthreads();
    }
    if (t < 16) cs[blockIdx.x * 16 + t] = (float)red[t];
}

// ---------------------------------------------------------------------------
// K3: per-row top-128 of |x*colsum| via 4-pass radix select, exact ties
// (lowest index first), masked x as bf16. Wave-level shfl scans.
// ---------------------------------------------------------------------------
__global__ __launch_bounds__(256) void topk_mask(const float* __restrict__ x,
                                                 const float* __restrict__ cs,
                                                 u16* __restrict__ xz) {
    __shared__ uint32_t hist[256];
    __shared__ uint32_t wtot[4];
    __shared__ uint32_t s_prefix, s_krem;

    const int b = blockIdx.x, t = threadIdx.x;
    const int lane = t & 63, wv = t >> 6;
    const float4* xrow = (const float4*)(x + (size_t)b * IN_DIM);
    const float4* csv  = (const float4*)cs;

    float    xr[16];
    uint32_t ul[16];
#pragma unroll
    for (int q = 0; q < 4; ++q) {
        float4 xv = xrow[t * 4 + q];
        float4 cv = csv[t * 4 + q];
        xr[q*4+0] = xv.x; xr[q*4+1] = xv.y; xr[q*4+2] = xv.z; xr[q*4+3] = xv.w;
        ul[q*4+0] = __builtin_bit_cast(uint32_t, xv.x * cv.x) & 0x7fffffffu;
        ul[q*4+1] = __builtin_bit_cast(uint32_t, xv.y * cv.y) & 0x7fffffffu;
        ul[q*4+2] = __builtin_bit_cast(uint32_t, xv.z * cv.z) & 0x7fffffffu;
        ul[q*4+3] = __builtin_bit_cast(uint32_t, xv.w * cv.w) & 0x7fffffffu;
    }
    if (t == 0) { s_prefix = 0u; s_krem = K_SEL; }
    __syncthreads();

#pragma unroll
    for (int p = 3; p >= 0; --p) {
        const int sh = p * 8;
        const uint32_t hi_mask = (p == 3) ? 0u : (0xFFFFFFFFu << (sh + 8));
        const uint32_t prefix = s_prefix;
        const uint32_t krem   = s_krem;
        hist[t] = 0u;
        __syncthreads();
#pragma unroll
        for (int j = 0; j < 16; ++j) {
            uint32_t u = ul[j];
            if ((u & hi_mask) == (prefix & hi_mask))
                atomicAdd(&hist[(u >> sh) & 255u], 1u);
        }
        __syncthreads();
        const uint32_t h = hist[t];
        uint32_t v = h;
#pragma unroll
        for (int off = 1; off < 64; off <<= 1) {
            uint32_t got = __shfl_down(v, off);
            if (lane + off < 64) v += got;
        }
        if (lane == 0) wtot[wv] = v;
        __syncthreads();
        uint32_t add = 0;
#pragma unroll
        for (int ww = 0; ww < 4; ++ww)
            if (ww > wv) add += wtot[ww];
        const uint32_t mysuf   = v + add;
        const uint32_t nextsuf = mysuf - h;
        if (mysuf >= krem && nextsuf < krem) {
            s_prefix = prefix | ((uint32_t)t << sh);
            s_krem   = krem - nextsuf;
        }
        __syncthreads();
    }
    const uint32_t T       = s_prefix;
    const uint32_t need_eq = s_krem;

    uint32_t cnt = 0;
#pragma unroll
    for (int j = 0; j < 16; ++j) cnt += (ul[j] == T) ? 1u : 0u;
    uint32_t inc = cnt;
#pragma unroll
    for (int off = 1; off < 64; off <<= 1) {
        uint32_t got = __shfl_up(inc, off);
        if (lane >= off) inc += got;
    }
    if (lane == 63) wtot[wv] = inc;
    __syncthreads();
    uint32_t wbase = 0;
#pragma unroll
    for (int ww = 0; ww < 4; ++ww)
        if (ww < wv) wbase += wtot[ww];
    const int base = (int)(inc + wbase - cnt);

    union { u16 us[16]; uint4 v4[2]; } ob;
    int eqseen = 0;
#pragma unroll
    for (int j = 0; j < 16; ++j) {
        uint32_t u = ul[j];
        bool drop = (u > T);
        if (u == T) {
            if (base + eqseen < (int)need_eq) drop = true;
            ++eqseen;
        }
        ob.us[j] = drop ? (u16)0 : f2bf(xr[j]);
    }
    uint4* dst = (uint4*)(xz + (size_t)b * IN_DIM + t * 16);
    dst[0] = ob.v4[0];
    dst[1] = ob.v4[1];
}

// ---------------------------------------------------------------------------
// K4: bf16 GEMM C = A @ B^T, 256x256 tile, BK=64, 8 waves (2Mx4N),
// r10 2-barrier pipelined schedule, MFMA shape 32x32x16 (2382 TF ceiling
// vs 2075 at 16x16x32; halves MFMA inst count, same reads/bytes/barriers).
// Per wave: 4 m-tiles x 2 n-tiles of 32x32 (f32x16 acc each = 128 VGPR).
// A-frag: row=lane&31, k=(lane>>5)*8+j. C/D: col=lane&31,
// row=(reg&3)+8*(reg>>2)+4*(lane>>5)  [m74/m101].
// Swizzled read col for k-step ks (16 elems): ((ks*2+(l>>5)) ^ (l&7))*8.
// Schedule/staging/vmcnt/WAR ledger identical to r10.
// ---------------------------------------------------------------------------
#define NT 64

__global__ __launch_bounds__(512, 2) void gemm_pl(const u16* __restrict__ A,
                                                  const u16* __restrict__ Bm,
                                                  float* __restrict__ C) {
    __shared__ u16 lds_[65536];   // 128 KB

    const int bid = blockIdx.x;
    const int swz = (bid & 7) * 32 + (bid >> 3);   // 256 blocks, 8 XCDs
    const int m0 = (swz >> 4) * 256, n0 = (swz & 15) * 256;

    const int t = threadIdx.x;
    const int l = t & 63;
    const int w = t >> 6;
    const int wm = w >> 2, wn = w & 3;
    const int r31 = l & 31;            // operand row within 32-tile
    const int jb  = l >> 5;            // k-chunk base (0/1)
    const int x7  = l & 7;             // row&7 for swizzle

    const int cswz = ((t & 7) ^ ((t >> 3) & 7)) * 8;   // staging src col (elems)
    // swizzled read col per k-step ks=0..3
    int kcol[4];
#pragma unroll
    for (int ks = 0; ks < 4; ++ks) kcol[ks] = ((ks * 2 + jb) ^ x7) * 8;

    f32x16 acc[4][2];
#pragma unroll
    for (int i = 0; i < 4; ++i)
#pragma unroll
        for (int j = 0; j < 2; ++j)
#pragma unroll
            for (int e = 0; e < 16; ++e) acc[i][j][e] = 0.f;

#define GLOAD(g, off_bytes)                                                     \
    __builtin_amdgcn_global_load_lds(                                           \
        (const __attribute__((address_space(1))) void*)(g),                     \
        (__attribute__((address_space(3))) void*)(((char*)lds_) + (off_bytes)), \
        16, 0, 0)

    // A region r: rows {g*128 + r*64 .. +64} for g=0,1 -> 16KB
    auto stA = [&](int kb, int r, int kt) {
#pragma unroll
        for (int g = 0; g < 2; ++g)
            GLOAD(A + (size_t)(m0 + g * 128 + r * 64 + (t >> 3)) * IN_DIM + kt + cswz,
                  kb * 65536 + r * 16384 + g * 8192 + t * 16);
    };
    // B region r: rows {r*128 + g*64 .. +64} for g=0,1 -> 16KB
    auto stB = [&](int kb, int r, int kt) {
#pragma unroll
        for (int g = 0; g < 2; ++g)
            GLOAD(Bm + (size_t)(n0 + r * 128 + g * 64 + (t >> 3)) * IN_DIM + kt + cswz,
                  kb * 65536 + 32768 + r * 16384 + g * 8192 + t * 16);
    };

    // A frag (qm = m-region 0/1, kh = k-half 0/1): 2 m-tiles x 2 k-steps
    auto rdA = [&](bf16x8 (&dst)[2][2], int bufo, int qm, int kh) {
#pragma unroll
        for (int m2 = 0; m2 < 2; ++m2)
#pragma unroll
            for (int ki = 0; ki < 2; ++ki)
                dst[m2][ki] = *(const bf16x8*)&lds_[bufo + qm * 8192 + wm * 4096
                    + (m2 * 32 + r31) * 64 + kcol[kh * 2 + ki]];
    };
    // B frag (kh): 2 n-tiles x 2 k-steps
    auto rdB = [&](bf16x8 (&dst)[2][2], int bufo, int kh) {
#pragma unroll
        for (int n2 = 0; n2 < 2; ++n2)
#pragma unroll
            for (int ki = 0; ki < 2; ++ki)
                dst[n2][ki] = *(const bf16x8*)&lds_[bufo + 16384 + (wn >> 1) * 8192
                    + (wn & 1) * 4096 + (n2 * 32 + r31) * 64 + kcol[kh * 2 + ki]];
    };
    auto mm = [&](int qm, bf16x8 (&Aa)[2][2], bf16x8 (&Bb)[2][2]) {
        __builtin_amdgcn_s_setprio(1);
#pragma unroll
        for (int m2 = 0; m2 < 2; ++m2)
#pragma unroll
            for (int n2 = 0; n2 < 2; ++n2)
#pragma unroll
                for (int ki = 0; ki < 2; ++ki)
                    acc[qm * 2 + m2][n2] = __builtin_amdgcn_mfma_f32_32x32x16_bf16(
                        Aa[m2][ki], Bb[n2][ki], acc[qm * 2 + m2][n2], 0, 0, 0);
        __builtin_amdgcn_s_setprio(0);
        __builtin_amdgcn_sched_barrier(0);
    };

    bf16x8 a0k0[2][2], a0k1[2][2], a1k0[2][2], a1k1[2][2], bk0[2][2], bk1[2][2];

    // prologue: tile0 complete + S1,S2,S3(1); vmcnt(6); publish; pre-read.
    stA(0, 0, 0); stA(0, 1, 0); stB(0, 0, 0); stB(0, 1, 0);
    stA(1, 0, 64); stB(1, 0, 64); stB(1, 1, 64);
    asm volatile("s_waitcnt vmcnt(6)" ::: "memory");
    __builtin_amdgcn_s_barrier();
    asm volatile("" ::: "memory");
    rdA(a0k0, 0, 0, 0);
    rdB(bk0, 0, 0);

    for (int k = 0; k < NT; ++k) {
        const int bufo = (k & 1) * 32768;               // elem offset
        const int bufno = bufo ^ 32768;
        const int kbC = k & 1, kbN = kbC ^ 1;
        const int kt1 = (k + 1) * 64, kt2 = (k + 2) * 64;

        // ---- P0: reads a0k1,bk1(k); stage S4(k+1)=A-r1 -> bufN ----
        rdA(a0k1, bufo, 0, 1);
        rdB(bk1, bufo, 1);
        if (k < NT - 1) stA(kbN, 1, kt1);
        mm(0, a0k0, bk0);

        // ---- P1: reads a1k0,a1k1(k); WAR barrier ----
        rdA(a1k0, bufo, 1, 0);
        rdA(a1k1, bufo, 1, 1);
        mm(0, a0k1, bk1);
        asm volatile("" ::: "memory");
        __builtin_amdgcn_s_barrier();
        asm volatile("" ::: "memory");

        // ---- P2: stage S1(k+2)=A-r0 + S2(k+2)=B-r0; publish ----
        if (k < NT - 2) { stA(kbC, 0, kt2); stB(kbC, 0, kt2); }
        mm(1, a1k0, bk0);
        if (k < NT - 2) {
            asm volatile("s_waitcnt vmcnt(4)" ::: "memory");
        } else {
            asm volatile("s_waitcnt vmcnt(0)" ::: "memory");
        }
        __builtin_amdgcn_s_barrier();
        asm volatile("" ::: "memory");

        // ---- P3: reads a0k0,bk0(k+1) from bufN; stage S3(k+2)=B-r1 ----
        if (k < NT - 1) {
            rdA(a0k0, bufno, 0, 0);
            rdB(bk0, bufno, 0);
        }
        if (k < NT - 2) stB(kbC, 1, kt2);
        mm(1, a1k1, bk1);
    }
#undef GLOAD

    // epilogue: 32x32 C/D layout col=lane&31, row=(reg&3)+8*(reg>>2)+4*(l>>5)
#pragma unroll
    for (int mt = 0; mt < 4; ++mt)
#pragma unroll
        for (int nt = 0; nt < 2; ++nt)
#pragma unroll
            for (int r = 0; r < 16; ++r) {
                int row = m0 + wm * 128 + mt * 32 + (r & 3) + 8 * (r >> 2) + 4 * (l >> 5);
                int col = n0 + wn * 64 + nt * 32 + r31;
                C[(size_t)row * OUT_DIM + col] = acc[mt][nt][r];
            }
}

// ---------------------------------------------------------------------------
extern "C" void kernel_launch(void* const* d_in, const int* in_sizes, int n_in,
                              void* d_out, int out_size, void* d_ws, size_t ws_size,
                              hipStream_t stream) {
    const float* x = (const float*)d_in[0];
    const float* W = (const float*)d_in[1];
    float* out = (float*)d_out;

    char* ws = (char*)d_ws;
    u16*    Wb   = (u16*)ws;                                   // 32 MB bf16 W
    u16*    xz   = (u16*)(ws + (size_t)32 * 1024 * 1024);      // 32 MB bf16 masked x
    float*  cs   = (float*)(ws + (size_t)64 * 1024 * 1024);    // 16 KB colsum
    double* part = (double*)d_out;  // 16 MB partials, consumed before gemm writes

    colsum_conv<<<2048, 256, 0, stream>>>(W, part, Wb);
    colsum_final<<<256, 256, 0, stream>>>(part, cs);
    topk_mask<<<4096, 256, 0, stream>>>(x, cs, xz);
    gemm_pl<<<256, 512, 0, stream>>>(xz, Wb, out);
}

// Round 13
// 182.975 us; speedup vs baseline: 1.0667x; 1.0667x over previous
//
#include <hip/hip_runtime.h>
#include <hip/hip_bf16.h>
#include <stdint.h>

#define B_DIM   4096
#define IN_DIM  4096
#define OUT_DIM 4096
#define K_SEL   128

typedef unsigned short u16;
typedef __bf16 bf16x8 __attribute__((ext_vector_type(8)));
typedef float  f32x4  __attribute__((ext_vector_type(4)));

static __device__ __forceinline__ u16 f2bf(float f) {
    uint32_t u = __builtin_bit_cast(uint32_t, f);
    uint32_t r = (u + 0x7fffu + ((u >> 16) & 1u)) >> 16;
    return (u16)r;
}

// ---------------------------------------------------------------------------
// K1: column sums of W (fp64 partials over 8-row chunks) + W -> bf16.
// 2048 blocks = (4 col-chunks x 512 row-chunks); part = [512][4096] dbl (16MB).
// ---------------------------------------------------------------------------
__global__ __launch_bounds__(256) void colsum_conv(const float* __restrict__ W,
                                                   double* __restrict__ part,
                                                   u16* __restrict__ Wb) {
    int cb = blockIdx.x & 3;
    int rb = blockIdx.x >> 2;          // 0..511
    int c4 = cb * 256 + threadIdx.x;   // float4 index within a row
    int row0 = rb * 8;
    double s0 = 0.0, s1 = 0.0, s2 = 0.0, s3 = 0.0;
    for (int r = 0; r < 8; ++r) {
        const float4 v = ((const float4*)(W + (size_t)(row0 + r) * IN_DIM))[c4];
        s0 += (double)v.x; s1 += (double)v.y; s2 += (double)v.z; s3 += (double)v.w;
        ushort4 o;
        o.x = f2bf(v.x); o.y = f2bf(v.y); o.z = f2bf(v.z); o.w = f2bf(v.w);
        ((ushort4*)(Wb + (size_t)(row0 + r) * IN_DIM))[c4] = o;
    }
    double4 d; d.x = s0; d.y = s1; d.z = s2; d.w = s3;
    ((double4*)(part + (size_t)rb * IN_DIM))[c4] = d;
}

// 256 blocks x 256 threads: block handles 16 cols; 16 row-groups of 32.
__global__ __launch_bounds__(256) void colsum_final(const double* __restrict__ part,
                                                    float* __restrict__ cs) {
    __shared__ double red[256];
    const int t = threadIdx.x;
    const int c = blockIdx.x * 16 + (t & 15);
    const int g = t >> 4;              // 0..15
    double s = 0.0;
    for (int r = 0; r < 32; ++r) s += part[(size_t)(g * 32 + r) * IN_DIM + c];
    red[t] = s;
    __syncthreads();
    for (int off = 128; off >= 16; off >>= 1) {
        if (t < off) red[t] += red[t + off];
        __syncthreads();
    }
    if (t < 16) cs[blockIdx.x * 16 + t] = (float)red[t];
}

// ---------------------------------------------------------------------------
// K3: per-row top-128 of |x*colsum| via 4-pass radix select, exact ties
// (lowest index first), masked x as bf16. Wave-level shfl scans.
// ---------------------------------------------------------------------------
__global__ __launch_bounds__(256) void topk_mask(const float* __restrict__ x,
                                                 const float* __restrict__ cs,
                                                 u16* __restrict__ xz) {
    __shared__ uint32_t hist[256];
    __shared__ uint32_t wtot[4];
    __shared__ uint32_t s_prefix, s_krem;

    const int b = blockIdx.x, t = threadIdx.x;
    const int lane = t & 63, wv = t >> 6;
    const float4* xrow = (const float4*)(x + (size_t)b * IN_DIM);
    const float4* csv  = (const float4*)cs;

    float    xr[16];
    uint32_t ul[16];
#pragma unroll
    for (int q = 0; q < 4; ++q) {
        float4 xv = xrow[t * 4 + q];
        float4 cv = csv[t * 4 + q];
        xr[q*4+0] = xv.x; xr[q*4+1] = xv.y; xr[q*4+2] = xv.z; xr[q*4+3] = xv.w;
        ul[q*4+0] = __builtin_bit_cast(uint32_t, xv.x * cv.x) & 0x7fffffffu;
        ul[q*4+1] = __builtin_bit_cast(uint32_t, xv.y * cv.y) & 0x7fffffffu;
        ul[q*4+2] = __builtin_bit_cast(uint32_t, xv.z * cv.z) & 0x7fffffffu;
        ul[q*4+3] = __builtin_bit_cast(uint32_t, xv.w * cv.w) & 0x7fffffffu;
    }
    if (t == 0) { s_prefix = 0u; s_krem = K_SEL; }
    __syncthreads();

#pragma unroll
    for (int p = 3; p >= 0; --p) {
        const int sh = p * 8;
        const uint32_t hi_mask = (p == 3) ? 0u : (0xFFFFFFFFu << (sh + 8));
        const uint32_t prefix = s_prefix;
        const uint32_t krem   = s_krem;
        hist[t] = 0u;
        __syncthreads();
#pragma unroll
        for (int j = 0; j < 16; ++j) {
            uint32_t u = ul[j];
            if ((u & hi_mask) == (prefix & hi_mask))
                atomicAdd(&hist[(u >> sh) & 255u], 1u);
        }
        __syncthreads();
        const uint32_t h = hist[t];
        uint32_t v = h;
#pragma unroll
        for (int off = 1; off < 64; off <<= 1) {
            uint32_t got = __shfl_down(v, off);
            if (lane + off < 64) v += got;
        }
        if (lane == 0) wtot[wv] = v;
        __syncthreads();
        uint32_t add = 0;
#pragma unroll
        for (int ww = 0; ww < 4; ++ww)
            if (ww > wv) add += wtot[ww];
        const uint32_t mysuf   = v + add;
        const uint32_t nextsuf = mysuf - h;
        if (mysuf >= krem && nextsuf < krem) {
            s_prefix = prefix | ((uint32_t)t << sh);
            s_krem   = krem - nextsuf;
        }
        __syncthreads();
    }
    const uint32_t T       = s_prefix;
    const uint32_t need_eq = s_krem;

    uint32_t cnt = 0;
#pragma unroll
    for (int j = 0; j < 16; ++j) cnt += (ul[j] == T) ? 1u : 0u;
    uint32_t inc = cnt;
#pragma unroll
    for (int off = 1; off < 64; off <<= 1) {
        uint32_t got = __shfl_up(inc, off);
        if (lane >= off) inc += got;
    }
    if (lane == 63) wtot[wv] = inc;
    __syncthreads();
    uint32_t wbase = 0;
#pragma unroll
    for (int ww = 0; ww < 4; ++ww)
        if (ww < wv) wbase += wtot[ww];
    const int base = (int)(inc + wbase - cnt);

    union { u16 us[16]; uint4 v4[2]; } ob;
    int eqseen = 0;
#pragma unroll
    for (int j = 0; j < 16; ++j) {
        uint32_t u = ul[j];
        bool drop = (u > T);
        if (u == T) {
            if (base + eqseen < (int)need_eq) drop = true;
            ++eqseen;
        }
        ob.us[j] = drop ? (u16)0 : f2bf(xr[j]);
    }
    uint4* dst = (uint4*)(xz + (size_t)b * IN_DIM + t * 16);
    dst[0] = ob.v4[0];
    dst[1] = ob.v4[1];
}

// ---------------------------------------------------------------------------
// K4: bf16 GEMM C = A @ B^T, 256x256 tile, BK=64, 8 waves (2Mx4N).
// Pipelined frags, TWO barriers per tile (r10/r11 structure — best measured):
//   P0: rd a0k1,bk1; stage S4(k+1)=A-r1->bufN; mm(a0k0,bk0)
//   P1: rd a1k0,a1k1; mm(a0k1,bk1);                [BARRIER: WAR]
//   P2: stage S1(k+2)=A-r0 + S2(k+2)=B-r0; mm(a1k0,bk0); vmcnt(4) [BARRIER]
//   P3: rd a0k0,bk0 (k+1, bufN); stage S3(k+2)=B-r1; mm(a1k1,bk1)
// WAR/RAW ledger as r10. T2 XOR-swizzle (0 conflicts), T5 setprio.
// MFMA 16x16x32 (32x32x16 regressed: +12.6M bank conflicts, r12).
// ---------------------------------------------------------------------------
#define NT 64

__global__ __launch_bounds__(512, 2) void gemm_pl(const u16* __restrict__ A,
                                                  const u16* __restrict__ Bm,
                                                  float* __restrict__ C) {
    __shared__ u16 lds_[65536];   // 128 KB

    const int bid = blockIdx.x;
    const int swz = (bid & 7) * 32 + (bid >> 3);   // 256 blocks, 8 XCDs
    const int m0 = (swz >> 4) * 256, n0 = (swz & 15) * 256;

    const int t = threadIdx.x;
    const int l = t & 63;
    const int lr = l & 15, lk = l >> 4;
    const int w = t >> 6;
    const int wm = w >> 2, wn = w & 3;

    const int cswz = ((t & 7) ^ ((t >> 3) & 7)) * 8;   // staging src col (elems)
    const int c0   = (lk ^ (lr & 7)) * 8;              // swizzled col, ks=0
    const int c1   = c0 ^ 32;                          // ks=1

    f32x4 acc[8][4];
#pragma unroll
    for (int i = 0; i < 8; ++i)
#pragma unroll
        for (int j = 0; j < 4; ++j) acc[i][j] = f32x4{0.f, 0.f, 0.f, 0.f};

#define GLOAD(g, off_bytes)                                                     \
    __builtin_amdgcn_global_load_lds(                                           \
        (const __attribute__((address_space(1))) void*)(g),                     \
        (__attribute__((address_space(3))) void*)(((char*)lds_) + (off_bytes)), \
        16, 0, 0)

    auto stA = [&](int kb, int r, int kt) {
#pragma unroll
        for (int g = 0; g < 2; ++g)
            GLOAD(A + (size_t)(m0 + g * 128 + r * 64 + (t >> 3)) * IN_DIM + kt + cswz,
                  kb * 65536 + r * 16384 + g * 8192 + t * 16);
    };
    auto stB = [&](int kb, int r, int kt) {
#pragma unroll
        for (int g = 0; g < 2; ++g)
            GLOAD(Bm + (size_t)(n0 + r * 128 + g * 64 + (t >> 3)) * IN_DIM + kt + cswz,
                  kb * 65536 + 32768 + r * 16384 + g * 8192 + t * 16);
    };

    auto rdA = [&](bf16x8 (&dst)[4], int bufo, int qm, int c) {
#pragma unroll
        for (int mi = 0; mi < 4; ++mi)
            dst[mi] = *(const bf16x8*)&lds_[bufo + qm * 8192 + wm * 4096 + lr * 64 + mi * 1024 + c];
    };
    auto rdB = [&](bf16x8 (&dst)[4], int bufo, int c) {
#pragma unroll
        for (int ni = 0; ni < 4; ++ni)
            dst[ni] = *(const bf16x8*)&lds_[bufo + 16384 + (wn >> 1) * 8192 + (wn & 1) * 4096 + lr * 64 + ni * 1024 + c];
    };
    auto mm = [&](int base, bf16x8 (&Aa)[4], bf16x8 (&Bb)[4]) {
        __builtin_amdgcn_s_setprio(1);
#pragma unroll
        for (int mi = 0; mi < 4; ++mi)
#pragma unroll
            for (int ni = 0; ni < 4; ++ni)
                acc[base + mi][ni] = __builtin_amdgcn_mfma_f32_16x16x32_bf16(
                    Aa[mi], Bb[ni], acc[base + mi][ni], 0, 0, 0);
        __builtin_amdgcn_s_setprio(0);
        __builtin_amdgcn_sched_barrier(0);
    };

    bf16x8 a0k0[4], a0k1[4], a1k0[4], a1k1[4], bk0[4], bk1[4];

    stA(0, 0, 0); stA(0, 1, 0); stB(0, 0, 0); stB(0, 1, 0);
    stA(1, 0, 64); stB(1, 0, 64); stB(1, 1, 64);
    asm volatile("s_waitcnt vmcnt(6)" ::: "memory");
    __builtin_amdgcn_s_barrier();
    asm volatile("" ::: "memory");
    rdA(a0k0, 0, 0, c0);
    rdB(bk0, 0, c0);

    for (int k = 0; k < NT; ++k) {
        const int bufo = (k & 1) * 32768;               // elem offset
        const int bufno = bufo ^ 32768;
        const int kbC = k & 1, kbN = kbC ^ 1;
        const int kt1 = (k + 1) * 64, kt2 = (k + 2) * 64;

        // ---- P0: reads a0k1,bk1(k); stage S4(k+1)=A-r1 -> bufN ----
        rdA(a0k1, bufo, 0, c1);
        rdB(bk1, bufo, c1);
        if (k < NT - 1) stA(kbN, 1, kt1);
        mm(0, a0k0, bk0);

        // ---- P1: reads a1k0,a1k1(k); WAR barrier ----
        rdA(a1k0, bufo, 1, c0);
        rdA(a1k1, bufo, 1, c1);
        mm(0, a0k1, bk1);
        asm volatile("" ::: "memory");
        __builtin_amdgcn_s_barrier();
        asm volatile("" ::: "memory");

        // ---- P2: stage S1(k+2)=A-r0 + S2(k+2)=B-r0; publish ----
        if (k < NT - 2) { stA(kbC, 0, kt2); stB(kbC, 0, kt2); }
        mm(4, a1k0, bk0);
        if (k < NT - 2) {
            asm volatile("s_waitcnt vmcnt(4)" ::: "memory");
        } else {
            asm volatile("s_waitcnt vmcnt(0)" ::: "memory");
        }
        __builtin_amdgcn_s_barrier();
        asm volatile("" ::: "memory");

        // ---- P3: reads a0k0,bk0(k+1) from bufN; stage S3(k+2)=B-r1 ----
        if (k < NT - 1) {
            rdA(a0k0, bufno, 0, c0);
            rdB(bk0, bufno, c0);
        }
        if (k < NT - 2) stB(kbC, 1, kt2);
        mm(4, a1k1, bk1);
    }
#undef GLOAD

    // epilogue: C/D layout col = lane&15, row = (lane>>4)*4 + r
#pragma unroll
    for (int gmi = 0; gmi < 8; ++gmi)
#pragma unroll
        for (int ni = 0; ni < 4; ++ni)
#pragma unroll
            for (int r = 0; r < 4; ++r) {
                int row = m0 + wm * 128 + (gmi >> 2) * 64 + (gmi & 3) * 16 + lk * 4 + r;
                int col = n0 + wn * 64 + ni * 16 + lr;
                C[(size_t)row * OUT_DIM + col] = acc[gmi][ni][r];
            }
}

// ---------------------------------------------------------------------------
extern "C" void kernel_launch(void* const* d_in, const int* in_sizes, int n_in,
                              void* d_out, int out_size, void* d_ws, size_t ws_size,
                              hipStream_t stream) {
    const float* x = (const float*)d_in[0];
    const float* W = (const float*)d_in[1];
    float* out = (float*)d_out;

    char* ws = (char*)d_ws;
    u16*    Wb   = (u16*)ws;                                   // 32 MB bf16 W
    u16*    xz   = (u16*)(ws + (size_t)32 * 1024 * 1024);      // 32 MB bf16 masked x
    float*  cs   = (float*)(ws + (size_t)64 * 1024 * 1024);    // 16 KB colsum
    double* part = (double*)d_out;  // 16 MB partials, consumed before gemm writes

    colsum_conv<<<2048, 256, 0, stream>>>(W, part, Wb);
    colsum_final<<<256, 256, 0, stream>>>(part, cs);
    topk_mask<<<4096, 256, 0, stream>>>(x, cs, xz);
    gemm_pl<<<256, 512, 0, stream>>>(xz, Wb, out);
}

// Round 14
// 179.061 us; speedup vs baseline: 1.0900x; 1.0219x over previous
//
#include <hip/hip_runtime.h>
#include <hip/hip_bf16.h>
#include <stdint.h>

#define B_DIM   4096
#define IN_DIM  4096
#define OUT_DIM 4096
#define K_SEL   128

typedef unsigned short u16;
typedef __bf16 bf16x8 __attribute__((ext_vector_type(8)));
typedef float  f32x4  __attribute__((ext_vector_type(4)));

static __device__ __forceinline__ u16 f2bf(float f) {
    uint32_t u = __builtin_bit_cast(uint32_t, f);
    uint32_t r = (u + 0x7fffu + ((u >> 16) & 1u)) >> 16;
    return (u16)r;
}

// ---------------------------------------------------------------------------
// K1: column sums of W (fp64 partials over 32-row chunks) + W -> bf16.
// 512 blocks; float4 loads. part = [128][4096] doubles (4MB) in d_out.
// (r11 measured config — 2048 blocks/16MB partials cost +4.7us, r13.)
// ---------------------------------------------------------------------------
__global__ __launch_bounds__(256) void colsum_conv(const float* __restrict__ W,
                                                   double* __restrict__ part,
                                                   u16* __restrict__ Wb) {
    int cb = blockIdx.x & 3;
    int rb = blockIdx.x >> 2;          // 0..127
    int c4 = cb * 256 + threadIdx.x;   // float4 index within a row
    int row0 = rb * 32;
    double s0 = 0.0, s1 = 0.0, s2 = 0.0, s3 = 0.0;
    for (int r = 0; r < 32; ++r) {
        const float4 v = ((const float4*)(W + (size_t)(row0 + r) * IN_DIM))[c4];
        s0 += (double)v.x; s1 += (double)v.y; s2 += (double)v.z; s3 += (double)v.w;
        ushort4 o;
        o.x = f2bf(v.x); o.y = f2bf(v.y); o.z = f2bf(v.z); o.w = f2bf(v.w);
        ((ushort4*)(Wb + (size_t)(row0 + r) * IN_DIM))[c4] = o;
    }
    double4 d; d.x = s0; d.y = s1; d.z = s2; d.w = s3;
    ((double4*)(part + (size_t)rb * IN_DIM))[c4] = d;
}

// 256 blocks x 256 threads: block handles 16 cols; 16 row-groups of 8.
__global__ __launch_bounds__(256) void colsum_final(const double* __restrict__ part,
                                                    float* __restrict__ cs) {
    __shared__ double red[256];
    const int t = threadIdx.x;
    const int c = blockIdx.x * 16 + (t & 15);
    const int g = t >> 4;              // 0..15
    double s = 0.0;
    for (int r = 0; r < 8; ++r) s += part[(size_t)(g * 8 + r) * IN_DIM + c];
    red[t] = s;
    __syncthreads();
    for (int off = 128; off >= 16; off >>= 1) {
        if (t < off) red[t] += red[t + off];
        __syncthreads();
    }
    if (t < 16) cs[blockIdx.x * 16 + t] = (float)red[t];
}

// ---------------------------------------------------------------------------
// K3: per-row top-128 of |x*colsum| via 4-pass radix select, exact ties
// (lowest index first), masked x as bf16. Wave-level shfl scans.
// PER-WAVE split histograms: first-pass digits (exponent byte of |N*N|)
// concentrate in ~3 bins -> LDS atomic serialization; 4 copies cut it 4x.
// ---------------------------------------------------------------------------
__global__ __launch_bounds__(256) void topk_mask(const float* __restrict__ x,
                                                 const float* __restrict__ cs,
                                                 u16* __restrict__ xz) {
    __shared__ uint32_t hist[4 * 256];
    __shared__ uint32_t wtot[4];
    __shared__ uint32_t s_prefix, s_krem;

    const int b = blockIdx.x, t = threadIdx.x;
    const int lane = t & 63, wv = t >> 6;
    const float4* xrow = (const float4*)(x + (size_t)b * IN_DIM);
    const float4* csv  = (const float4*)cs;

    float    xr[16];
    uint32_t ul[16];
#pragma unroll
    for (int q = 0; q < 4; ++q) {
        float4 xv = xrow[t * 4 + q];
        float4 cv = csv[t * 4 + q];
        xr[q*4+0] = xv.x; xr[q*4+1] = xv.y; xr[q*4+2] = xv.z; xr[q*4+3] = xv.w;
        ul[q*4+0] = __builtin_bit_cast(uint32_t, xv.x * cv.x) & 0x7fffffffu;
        ul[q*4+1] = __builtin_bit_cast(uint32_t, xv.y * cv.y) & 0x7fffffffu;
        ul[q*4+2] = __builtin_bit_cast(uint32_t, xv.z * cv.z) & 0x7fffffffu;
        ul[q*4+3] = __builtin_bit_cast(uint32_t, xv.w * cv.w) & 0x7fffffffu;
    }
    if (t == 0) { s_prefix = 0u; s_krem = K_SEL; }
    __syncthreads();

#pragma unroll
    for (int p = 3; p >= 0; --p) {
        const int sh = p * 8;
        const uint32_t hi_mask = (p == 3) ? 0u : (0xFFFFFFFFu << (sh + 8));
        const uint32_t prefix = s_prefix;
        const uint32_t krem   = s_krem;
#pragma unroll
        for (int ww = 0; ww < 4; ++ww) hist[ww * 256 + t] = 0u;
        __syncthreads();
#pragma unroll
        for (int j = 0; j < 16; ++j) {
            uint32_t u = ul[j];
            if ((u & hi_mask) == (prefix & hi_mask))
                atomicAdd(&hist[wv * 256 + ((u >> sh) & 255u)], 1u);
        }
        __syncthreads();
        const uint32_t h = hist[t] + hist[256 + t] + hist[512 + t] + hist[768 + t];
        uint32_t v = h;
#pragma unroll
        for (int off = 1; off < 64; off <<= 1) {
            uint32_t got = __shfl_down(v, off);
            if (lane + off < 64) v += got;
        }
        if (lane == 0) wtot[wv] = v;
        __syncthreads();
        uint32_t add = 0;
#pragma unroll
        for (int ww = 0; ww < 4; ++ww)
            if (ww > wv) add += wtot[ww];
        const uint32_t mysuf   = v + add;
        const uint32_t nextsuf = mysuf - h;
        if (mysuf >= krem && nextsuf < krem) {
            s_prefix = prefix | ((uint32_t)t << sh);
            s_krem   = krem - nextsuf;
        }
        __syncthreads();
    }
    const uint32_t T       = s_prefix;
    const uint32_t need_eq = s_krem;

    uint32_t cnt = 0;
#pragma unroll
    for (int j = 0; j < 16; ++j) cnt += (ul[j] == T) ? 1u : 0u;
    uint32_t inc = cnt;
#pragma unroll
    for (int off = 1; off < 64; off <<= 1) {
        uint32_t got = __shfl_up(inc, off);
        if (lane >= off) inc += got;
    }
    if (lane == 63) wtot[wv] = inc;
    __syncthreads();
    uint32_t wbase = 0;
#pragma unroll
    for (int ww = 0; ww < 4; ++ww)
        if (ww < wv) wbase += wtot[ww];
    const int base = (int)(inc + wbase - cnt);

    union { u16 us[16]; uint4 v4[2]; } ob;
    int eqseen = 0;
#pragma unroll
    for (int j = 0; j < 16; ++j) {
        uint32_t u = ul[j];
        bool drop = (u > T);
        if (u == T) {
            if (base + eqseen < (int)need_eq) drop = true;
            ++eqseen;
        }
        ob.us[j] = drop ? (u16)0 : f2bf(xr[j]);
    }
    uint4* dst = (uint4*)(xz + (size_t)b * IN_DIM + t * 16);
    dst[0] = ob.v4[0];
    dst[1] = ob.v4[1];
}

// ---------------------------------------------------------------------------
// K4: bf16 GEMM C = A @ B^T, 256x256 tile, BK=64, 8 waves (2Mx4N).
// Pipelined frags, TWO barriers per tile (r10/r11 structure — best measured):
//   P0: rd a0k1,bk1; stage S4(k+1)=A-r1->bufN; mm(a0k0,bk0)
//   P1: rd a1k0,a1k1; mm(a0k1,bk1);                [BARRIER: WAR]
//   P2: stage S1(k+2)=A-r0 + S2(k+2)=B-r0; mm(a1k0,bk0); vmcnt(4) [BARRIER]
//   P3: rd a0k0,bk0 (k+1, bufN); stage S3(k+2)=B-r1; mm(a1k1,bk1)
// WAR/RAW ledger as r10. T2 XOR-swizzle (0 conflicts), T5 setprio.
// MFMA 16x16x32 (32x32x16 regressed: +12.6M bank conflicts, r12).
// ---------------------------------------------------------------------------
#define NT 64

__global__ __launch_bounds__(512, 2) void gemm_pl(const u16* __restrict__ A,
                                                  const u16* __restrict__ Bm,
                                                  float* __restrict__ C) {
    __shared__ u16 lds_[65536];   // 128 KB

    const int bid = blockIdx.x;
    const int swz = (bid & 7) * 32 + (bid >> 3);   // 256 blocks, 8 XCDs
    const int m0 = (swz >> 4) * 256, n0 = (swz & 15) * 256;

    const int t = threadIdx.x;
    const int l = t & 63;
    const int lr = l & 15, lk = l >> 4;
    const int w = t >> 6;
    const int wm = w >> 2, wn = w & 3;

    const int cswz = ((t & 7) ^ ((t >> 3) & 7)) * 8;   // staging src col (elems)
    const int c0   = (lk ^ (lr & 7)) * 8;              // swizzled col, ks=0
    const int c1   = c0 ^ 32;                          // ks=1

    f32x4 acc[8][4];
#pragma unroll
    for (int i = 0; i < 8; ++i)
#pragma unroll
        for (int j = 0; j < 4; ++j) acc[i][j] = f32x4{0.f, 0.f, 0.f, 0.f};

#define GLOAD(g, off_bytes)                                                     \
    __builtin_amdgcn_global_load_lds(                                           \
        (const __attribute__((address_space(1))) void*)(g),                     \
        (__attribute__((address_space(3))) void*)(((char*)lds_) + (off_bytes)), \
        16, 0, 0)

    auto stA = [&](int kb, int r, int kt) {
#pragma unroll
        for (int g = 0; g < 2; ++g)
            GLOAD(A + (size_t)(m0 + g * 128 + r * 64 + (t >> 3)) * IN_DIM + kt + cswz,
                  kb * 65536 + r * 16384 + g * 8192 + t * 16);
    };
    auto stB = [&](int kb, int r, int kt) {
#pragma unroll
        for (int g = 0; g < 2; ++g)
            GLOAD(Bm + (size_t)(n0 + r * 128 + g * 64 + (t >> 3)) * IN_DIM + kt + cswz,
                  kb * 65536 + 32768 + r * 16384 + g * 8192 + t * 16);
    };

    auto rdA = [&](bf16x8 (&dst)[4], int bufo, int qm, int c) {
#pragma unroll
        for (int mi = 0; mi < 4; ++mi)
            dst[mi] = *(const bf16x8*)&lds_[bufo + qm * 8192 + wm * 4096 + lr * 64 + mi * 1024 + c];
    };
    auto rdB = [&](bf16x8 (&dst)[4], int bufo, int c) {
#pragma unroll
        for (int ni = 0; ni < 4; ++ni)
            dst[ni] = *(const bf16x8*)&lds_[bufo + 16384 + (wn >> 1) * 8192 + (wn & 1) * 4096 + lr * 64 + ni * 1024 + c];
    };
    auto mm = [&](int base, bf16x8 (&Aa)[4], bf16x8 (&Bb)[4]) {
        __builtin_amdgcn_s_setprio(1);
#pragma unroll
        for (int mi = 0; mi < 4; ++mi)
#pragma unroll
            for (int ni = 0; ni < 4; ++ni)
                acc[base + mi][ni] = __builtin_amdgcn_mfma_f32_16x16x32_bf16(
                    Aa[mi], Bb[ni], acc[base + mi][ni], 0, 0, 0);
        __builtin_amdgcn_s_setprio(0);
        __builtin_amdgcn_sched_barrier(0);
    };

    bf16x8 a0k0[4], a0k1[4], a1k0[4], a1k1[4], bk0[4], bk1[4];

    stA(0, 0, 0); stA(0, 1, 0); stB(0, 0, 0); stB(0, 1, 0);
    stA(1, 0, 64); stB(1, 0, 64); stB(1, 1, 64);
    asm volatile("s_waitcnt vmcnt(6)" ::: "memory");
    __builtin_amdgcn_s_barrier();
    asm volatile("" ::: "memory");
    rdA(a0k0, 0, 0, c0);
    rdB(bk0, 0, c0);

    for (int k = 0; k < NT; ++k) {
        const int bufo = (k & 1) * 32768;               // elem offset
        const int bufno = bufo ^ 32768;
        const int kbC = k & 1, kbN = kbC ^ 1;
        const int kt1 = (k + 1) * 64, kt2 = (k + 2) * 64;

        // ---- P0: reads a0k1,bk1(k); stage S4(k+1)=A-r1 -> bufN ----
        rdA(a0k1, bufo, 0, c1);
        rdB(bk1, bufo, c1);
        if (k < NT - 1) stA(kbN, 1, kt1);
        mm(0, a0k0, bk0);

        // ---- P1: reads a1k0,a1k1(k); WAR barrier ----
        rdA(a1k0, bufo, 1, c0);
        rdA(a1k1, bufo, 1, c1);
        mm(0, a0k1, bk1);
        asm volatile("" ::: "memory");
        __builtin_amdgcn_s_barrier();
        asm volatile("" ::: "memory");

        // ---- P2: stage S1(k+2)=A-r0 + S2(k+2)=B-r0; publish ----
        if (k < NT - 2) { stA(kbC, 0, kt2); stB(kbC, 0, kt2); }
        mm(4, a1k0, bk0);
        if (k < NT - 2) {
            asm volatile("s_waitcnt vmcnt(4)" ::: "memory");
        } else {
            asm volatile("s_waitcnt vmcnt(0)" ::: "memory");
        }
        __builtin_amdgcn_s_barrier();
        asm volatile("" ::: "memory");

        // ---- P3: reads a0k0,bk0(k+1) from bufN; stage S3(k+2)=B-r1 ----
        if (k < NT - 1) {
            rdA(a0k0, bufno, 0, c0);
            rdB(bk0, bufno, c0);
        }
        if (k < NT - 2) stB(kbC, 1, kt2);
        mm(4, a1k1, bk1);
    }
#undef GLOAD

    // epilogue: C/D layout col = lane&15, row = (lane>>4)*4 + r
#pragma unroll
    for (int gmi = 0; gmi < 8; ++gmi)
#pragma unroll
        for (int ni = 0; ni < 4; ++ni)
#pragma unroll
            for (int r = 0; r < 4; ++r) {
                int row = m0 + wm * 128 + (gmi >> 2) * 64 + (gmi & 3) * 16 + lk * 4 + r;
                int col = n0 + wn * 64 + ni * 16 + lr;
                C[(size_t)row * OUT_DIM + col] = acc[gmi][ni][r];
            }
}

// ---------------------------------------------------------------------------
extern "C" void kernel_launch(void* const* d_in, const int* in_sizes, int n_in,
                              void* d_out, int out_size, void* d_ws, size_t ws_size,
                              hipStream_t stream) {
    const float* x = (const float*)d_in[0];
    const float* W = (const float*)d_in[1];
    float* out = (float*)d_out;

    char* ws = (char*)d_ws;
    u16*    Wb   = (u16*)ws;                                   // 32 MB bf16 W
    u16*    xz   = (u16*)(ws + (size_t)32 * 1024 * 1024);      // 32 MB bf16 masked x
    float*  cs   = (float*)(ws + (size_t)64 * 1024 * 1024);    // 16 KB colsum
    double* part = (double*)d_out;  // 4 MB partials, consumed before gemm writes

    colsum_conv<<<512, 256, 0, stream>>>(W, part, Wb);
    colsum_final<<<256, 256, 0, stream>>>(part, cs);
    topk_mask<<<4096, 256, 0, stream>>>(x, cs, xz);
    gemm_pl<<<256, 512, 0, stream>>>(xz, Wb, out);
}

// Round 15
// 178.227 us; speedup vs baseline: 1.0951x; 1.0047x over previous
//
#include <hip/hip_runtime.h>
#include <hip/hip_bf16.h>
#include <stdint.h>

#define B_DIM   4096
#define IN_DIM  4096
#define OUT_DIM 4096
#define K_SEL   128

typedef unsigned short u16;
typedef __bf16 bf16x8 __attribute__((ext_vector_type(8)));
typedef float  f32x4  __attribute__((ext_vector_type(4)));

static __device__ __forceinline__ u16 f2bf(float f) {
    uint32_t u = __builtin_bit_cast(uint32_t, f);
    uint32_t r = (u + 0x7fffu + ((u >> 16) & 1u)) >> 16;
    return (u16)r;
}

// ---------------------------------------------------------------------------
// K1: column sums of W (fp64 partials over 32-row chunks) + W -> bf16.
// 512 blocks; float4 loads. part = [128][4096] doubles (4MB) in d_out.
// (Best measured config: 2048 blocks/16MB partials cost +4.7us — r12/r13.)
// ---------------------------------------------------------------------------
__global__ __launch_bounds__(256) void colsum_conv(const float* __restrict__ W,
                                                   double* __restrict__ part,
                                                   u16* __restrict__ Wb) {
    int cb = blockIdx.x & 3;
    int rb = blockIdx.x >> 2;          // 0..127
    int c4 = cb * 256 + threadIdx.x;   // float4 index within a row
    int row0 = rb * 32;
    double s0 = 0.0, s1 = 0.0, s2 = 0.0, s3 = 0.0;
    for (int r = 0; r < 32; ++r) {
        const float4 v = ((const float4*)(W + (size_t)(row0 + r) * IN_DIM))[c4];
        s0 += (double)v.x; s1 += (double)v.y; s2 += (double)v.z; s3 += (double)v.w;
        ushort4 o;
        o.x = f2bf(v.x); o.y = f2bf(v.y); o.z = f2bf(v.z); o.w = f2bf(v.w);
        ((ushort4*)(Wb + (size_t)(row0 + r) * IN_DIM))[c4] = o;
    }
    double4 d; d.x = s0; d.y = s1; d.z = s2; d.w = s3;
    ((double4*)(part + (size_t)rb * IN_DIM))[c4] = d;
}

// 256 blocks x 256 threads: block handles 16 cols; 16 row-groups of 8.
__global__ __launch_bounds__(256) void colsum_final(const double* __restrict__ part,
                                                    float* __restrict__ cs) {
    __shared__ double red[256];
    const int t = threadIdx.x;
    const int c = blockIdx.x * 16 + (t & 15);
    const int g = t >> 4;              // 0..15
    double s = 0.0;
    for (int r = 0; r < 8; ++r) s += part[(size_t)(g * 8 + r) * IN_DIM + c];
    red[t] = s;
    __syncthreads();
    for (int off = 128; off >= 16; off >>= 1) {
        if (t < off) red[t] += red[t + off];
        __syncthreads();
    }
    if (t < 16) cs[blockIdx.x * 16 + t] = (float)red[t];
}

// ---------------------------------------------------------------------------
// K3: per-row top-128 of |x*colsum| via 4-pass radix select, exact ties
// (lowest index first), masked x as bf16. Wave-level shfl scans.
// (Per-wave split histograms were null — r14; single hist is the 178.27 cfg.)
// ---------------------------------------------------------------------------
__global__ __launch_bounds__(256) void topk_mask(const float* __restrict__ x,
                                                 const float* __restrict__ cs,
                                                 u16* __restrict__ xz) {
    __shared__ uint32_t hist[256];
    __shared__ uint32_t wtot[4];
    __shared__ uint32_t s_prefix, s_krem;

    const int b = blockIdx.x, t = threadIdx.x;
    const int lane = t & 63, wv = t >> 6;
    const float4* xrow = (const float4*)(x + (size_t)b * IN_DIM);
    const float4* csv  = (const float4*)cs;

    float    xr[16];
    uint32_t ul[16];
#pragma unroll
    for (int q = 0; q < 4; ++q) {
        float4 xv = xrow[t * 4 + q];
        float4 cv = csv[t * 4 + q];
        xr[q*4+0] = xv.x; xr[q*4+1] = xv.y; xr[q*4+2] = xv.z; xr[q*4+3] = xv.w;
        ul[q*4+0] = __builtin_bit_cast(uint32_t, xv.x * cv.x) & 0x7fffffffu;
        ul[q*4+1] = __builtin_bit_cast(uint32_t, xv.y * cv.y) & 0x7fffffffu;
        ul[q*4+2] = __builtin_bit_cast(uint32_t, xv.z * cv.z) & 0x7fffffffu;
        ul[q*4+3] = __builtin_bit_cast(uint32_t, xv.w * cv.w) & 0x7fffffffu;
    }
    if (t == 0) { s_prefix = 0u; s_krem = K_SEL; }
    __syncthreads();

#pragma unroll
    for (int p = 3; p >= 0; --p) {
        const int sh = p * 8;
        const uint32_t hi_mask = (p == 3) ? 0u : (0xFFFFFFFFu << (sh + 8));
        const uint32_t prefix = s_prefix;
        const uint32_t krem   = s_krem;
        hist[t] = 0u;
        __syncthreads();
#pragma unroll
        for (int j = 0; j < 16; ++j) {
            uint32_t u = ul[j];
            if ((u & hi_mask) == (prefix & hi_mask))
                atomicAdd(&hist[(u >> sh) & 255u], 1u);
        }
        __syncthreads();
        const uint32_t h = hist[t];
        uint32_t v = h;
#pragma unroll
        for (int off = 1; off < 64; off <<= 1) {
            uint32_t got = __shfl_down(v, off);
            if (lane + off < 64) v += got;
        }
        if (lane == 0) wtot[wv] = v;
        __syncthreads();
        uint32_t add = 0;
#pragma unroll
        for (int ww = 0; ww < 4; ++ww)
            if (ww > wv) add += wtot[ww];
        const uint32_t mysuf   = v + add;
        const uint32_t nextsuf = mysuf - h;
        if (mysuf >= krem && nextsuf < krem) {
            s_prefix = prefix | ((uint32_t)t << sh);
            s_krem   = krem - nextsuf;
        }
        __syncthreads();
    }
    const uint32_t T       = s_prefix;
    const uint32_t need_eq = s_krem;

    uint32_t cnt = 0;
#pragma unroll
    for (int j = 0; j < 16; ++j) cnt += (ul[j] == T) ? 1u : 0u;
    uint32_t inc = cnt;
#pragma unroll
    for (int off = 1; off < 64; off <<= 1) {
        uint32_t got = __shfl_up(inc, off);
        if (lane >= off) inc += got;
    }
    if (lane == 63) wtot[wv] = inc;
    __syncthreads();
    uint32_t wbase = 0;
#pragma unroll
    for (int ww = 0; ww < 4; ++ww)
        if (ww < wv) wbase += wtot[ww];
    const int base = (int)(inc + wbase - cnt);

    union { u16 us[16]; uint4 v4[2]; } ob;
    int eqseen = 0;
#pragma unroll
    for (int j = 0; j < 16; ++j) {
        uint32_t u = ul[j];
        bool drop = (u > T);
        if (u == T) {
            if (base + eqseen < (int)need_eq) drop = true;
            ++eqseen;
        }
        ob.us[j] = drop ? (u16)0 : f2bf(xr[j]);
    }
    uint4* dst = (uint4*)(xz + (size_t)b * IN_DIM + t * 16);
    dst[0] = ob.v4[0];
    dst[1] = ob.v4[1];
}

// ---------------------------------------------------------------------------
// K4: bf16 GEMM C = A @ B^T, 256x256 tile, BK=64, 8 waves (2Mx4N).
// Pipelined frags, TWO barriers per tile (best measured structure):
//   P0: rd a0k1,bk1; stage S4(k+1)=A-r1->bufN; mm(a0k0,bk0)
//   P1: rd a1k0,a1k1; mm(a0k1,bk1);                [BARRIER: WAR]
//   P2: stage S1(k+2)=A-r0 + S2(k+2)=B-r0; mm(a1k0,bk0); vmcnt(4) [BARRIER]
//   P3: rd a0k0,bk0 (k+1, bufN); stage S3(k+2)=B-r1; mm(a1k1,bk1)
// WAR/RAW ledger as r10. T2 XOR-swizzle (0 conflicts), T5 setprio.
// MFMA 16x16x32 (32x32x16 regressed: +12.6M bank conflicts, r12).
// ---------------------------------------------------------------------------
#define NT 64

__global__ __launch_bounds__(512, 2) void gemm_pl(const u16* __restrict__ A,
                                                  const u16* __restrict__ Bm,
                                                  float* __restrict__ C) {
    __shared__ u16 lds_[65536];   // 128 KB

    const int bid = blockIdx.x;
    const int swz = (bid & 7) * 32 + (bid >> 3);   // 256 blocks, 8 XCDs
    const int m0 = (swz >> 4) * 256, n0 = (swz & 15) * 256;

    const int t = threadIdx.x;
    const int l = t & 63;
    const int lr = l & 15, lk = l >> 4;
    const int w = t >> 6;
    const int wm = w >> 2, wn = w & 3;

    const int cswz = ((t & 7) ^ ((t >> 3) & 7)) * 8;   // staging src col (elems)
    const int c0   = (lk ^ (lr & 7)) * 8;              // swizzled col, ks=0
    const int c1   = c0 ^ 32;                          // ks=1

    f32x4 acc[8][4];
#pragma unroll
    for (int i = 0; i < 8; ++i)
#pragma unroll
        for (int j = 0; j < 4; ++j) acc[i][j] = f32x4{0.f, 0.f, 0.f, 0.f};

#define GLOAD(g, off_bytes)                                                     \
    __builtin_amdgcn_global_load_lds(                                           \
        (const __attribute__((address_space(1))) void*)(g),                     \
        (__attribute__((address_space(3))) void*)(((char*)lds_) + (off_bytes)), \
        16, 0, 0)

    auto stA = [&](int kb, int r, int kt) {
#pragma unroll
        for (int g = 0; g < 2; ++g)
            GLOAD(A + (size_t)(m0 + g * 128 + r * 64 + (t >> 3)) * IN_DIM + kt + cswz,
                  kb * 65536 + r * 16384 + g * 8192 + t * 16);
    };
    auto stB = [&](int kb, int r, int kt) {
#pragma unroll
        for (int g = 0; g < 2; ++g)
            GLOAD(Bm + (size_t)(n0 + r * 128 + g * 64 + (t >> 3)) * IN_DIM + kt + cswz,
                  kb * 65536 + 32768 + r * 16384 + g * 8192 + t * 16);
    };

    auto rdA = [&](bf16x8 (&dst)[4], int bufo, int qm, int c) {
#pragma unroll
        for (int mi = 0; mi < 4; ++mi)
            dst[mi] = *(const bf16x8*)&lds_[bufo + qm * 8192 + wm * 4096 + lr * 64 + mi * 1024 + c];
    };
    auto rdB = [&](bf16x8 (&dst)[4], int bufo, int c) {
#pragma unroll
        for (int ni = 0; ni < 4; ++ni)
            dst[ni] = *(const bf16x8*)&lds_[bufo + 16384 + (wn >> 1) * 8192 + (wn & 1) * 4096 + lr * 64 + ni * 1024 + c];
    };
    auto mm = [&](int base, bf16x8 (&Aa)[4], bf16x8 (&Bb)[4]) {
        __builtin_amdgcn_s_setprio(1);
#pragma unroll
        for (int mi = 0; mi < 4; ++mi)
#pragma unroll
            for (int ni = 0; ni < 4; ++ni)
                acc[base + mi][ni] = __builtin_amdgcn_mfma_f32_16x16x32_bf16(
                    Aa[mi], Bb[ni], acc[base + mi][ni], 0, 0, 0);
        __builtin_amdgcn_s_setprio(0);
        __builtin_amdgcn_sched_barrier(0);
    };

    bf16x8 a0k0[4], a0k1[4], a1k0[4], a1k1[4], bk0[4], bk1[4];

    stA(0, 0, 0); stA(0, 1, 0); stB(0, 0, 0); stB(0, 1, 0);
    stA(1, 0, 64); stB(1, 0, 64); stB(1, 1, 64);
    asm volatile("s_waitcnt vmcnt(6)" ::: "memory");
    __builtin_amdgcn_s_barrier();
    asm volatile("" ::: "memory");
    rdA(a0k0, 0, 0, c0);
    rdB(bk0, 0, c0);

    for (int k = 0; k < NT; ++k) {
        const int bufo = (k & 1) * 32768;               // elem offset
        const int bufno = bufo ^ 32768;
        const int kbC = k & 1, kbN = kbC ^ 1;
        const int kt1 = (k + 1) * 64, kt2 = (k + 2) * 64;

        // ---- P0: reads a0k1,bk1(k); stage S4(k+1)=A-r1 -> bufN ----
        rdA(a0k1, bufo, 0, c1);
        rdB(bk1, bufo, c1);
        if (k < NT - 1) stA(kbN, 1, kt1);
        mm(0, a0k0, bk0);

        // ---- P1: reads a1k0,a1k1(k); WAR barrier ----
        rdA(a1k0, bufo, 1, c0);
        rdA(a1k1, bufo, 1, c1);
        mm(0, a0k1, bk1);
        asm volatile("" ::: "memory");
        __builtin_amdgcn_s_barrier();
        asm volatile("" ::: "memory");

        // ---- P2: stage S1(k+2)=A-r0 + S2(k+2)=B-r0; publish ----
        if (k < NT - 2) { stA(kbC, 0, kt2); stB(kbC, 0, kt2); }
        mm(4, a1k0, bk0);
        if (k < NT - 2) {
            asm volatile("s_waitcnt vmcnt(4)" ::: "memory");
        } else {
            asm volatile("s_waitcnt vmcnt(0)" ::: "memory");
        }
        __builtin_amdgcn_s_barrier();
        asm volatile("" ::: "memory");

        // ---- P3: reads a0k0,bk0(k+1) from bufN; stage S3(k+2)=B-r1 ----
        if (k < NT - 1) {
            rdA(a0k0, bufno, 0, c0);
            rdB(bk0, bufno, c0);
        }
        if (k < NT - 2) stB(kbC, 1, kt2);
        mm(4, a1k1, bk1);
    }
#undef GLOAD

    // epilogue: C/D layout col = lane&15, row = (lane>>4)*4 + r
#pragma unroll
    for (int gmi = 0; gmi < 8; ++gmi)
#pragma unroll
        for (int ni = 0; ni < 4; ++ni)
#pragma unroll
            for (int r = 0; r < 4; ++r) {
                int row = m0 + wm * 128 + (gmi >> 2) * 64 + (gmi & 3) * 16 + lk * 4 + r;
                int col = n0 + wn * 64 + ni * 16 + lr;
                C[(size_t)row * OUT_DIM + col] = acc[gmi][ni][r];
            }
}

// ---------------------------------------------------------------------------
extern "C" void kernel_launch(void* const* d_in, const int* in_sizes, int n_in,
                              void* d_out, int out_size, void* d_ws, size_t ws_size,
                              hipStream_t stream) {
    const float* x = (const float*)d_in[0];
    const float* W = (const float*)d_in[1];
    float* out = (float*)d_out;

    char* ws = (char*)d_ws;
    u16*    Wb   = (u16*)ws;                                   // 32 MB bf16 W
    u16*    xz   = (u16*)(ws + (size_t)32 * 1024 * 1024);      // 32 MB bf16 masked x
    float*  cs   = (float*)(ws + (size_t)64 * 1024 * 1024);    // 16 KB colsum
    double* part = (double*)d_out;  // 4 MB partials, consumed before gemm writes

    colsum_conv<<<512, 256, 0, stream>>>(W, part, Wb);
    colsum_final<<<256, 256, 0, stream>>>(part, cs);
    topk_mask<<<4096, 256, 0, stream>>>(x, cs, xz);
    gemm_pl<<<256, 512, 0, stream>>>(xz, Wb, out);
}